// Round 1
// baseline (320.354 us; speedup 1.0000x reference)
//
#include <hip/hip_runtime.h>

// Problem constants (from reference): B=16, C=512, H=W=14 (HW=196), D=8000.
#define B_DIM 16
#define C_DIM 512
#define HW_DIM 196
#define D_DIM 8000

// ---------------------------------------------------------------------------
// Kernel 1: extract count-sketch (hash, sign) from the dense sketch matrix.
// S is [C, D] row-major with exactly one nonzero (+-1) per row.
// One block per row; threads stride the row (coalesced); the single lane that
// sees a nonzero writes the result (no race: exactly one nonzero per row).
// ---------------------------------------------------------------------------
__global__ void extract_sketch(const float* __restrict__ S,
                               int* __restrict__ h, float* __restrict__ s) {
    const int row = blockIdx.x;
    const float* rowp = S + (size_t)row * D_DIM;
    for (int j = threadIdx.x; j < D_DIM; j += blockDim.x) {
        float v = rowp[j];
        if (v != 0.0f) {
            h[row] = j;
            s[row] = v;
        }
    }
}

// ---------------------------------------------------------------------------
// Kernel 2: per-batch Gram matrix (G = A * A^T, A = x[b] as [C=512, HW=196]
// row-major) fused with the count-sketch scatter epilogue:
//   out[b, (h1[c1]+h2[c2]) % D] += s1[c1]*s2[c2]*G[c1,c2]
// Block: 256 threads computing a 64x64 tile (4x4 per thread), K tiled by 32.
// Grid: (C/64, C/64, B) = (8, 8, 16) = 1024 blocks.
// ---------------------------------------------------------------------------
__global__ __launch_bounds__(256) void gram_scatter(
    const float* __restrict__ x,    // [B, C, HW]
    const int* __restrict__ h1, const float* __restrict__ s1,
    const int* __restrict__ h2, const float* __restrict__ s2,
    float* __restrict__ out) {      // [B, D] (pre-zeroed)
    const int b  = blockIdx.z;
    const int i0 = blockIdx.y * 64;   // c1 tile base
    const int j0 = blockIdx.x * 64;   // c2 tile base
    const float* A = x + (size_t)b * C_DIM * HW_DIM;

    __shared__ float As[64][33];      // +1 pad breaks stride-32 conflicts
    __shared__ float Bs[64][33];

    const int tid = threadIdx.x;
    const int tx = tid & 15;          // 16 x 16 thread layout
    const int ty = tid >> 4;

    float acc[4][4] = {};

    for (int k0 = 0; k0 < HW_DIM; k0 += 32) {
        // Load two 64x32 tiles: 2048 elements each, 8 per thread, coalesced
        // along k (consecutive tids read consecutive k).
        #pragma unroll
        for (int l = 0; l < 8; ++l) {
            int idx = l * 256 + tid;  // 0..2047
            int r   = idx >> 5;       // row within tile
            int kk  = idx & 31;       // k within chunk
            int k   = k0 + kk;
            float av = 0.0f, bv = 0.0f;
            if (k < HW_DIM) {
                av = A[(size_t)(i0 + r) * HW_DIM + k];
                bv = A[(size_t)(j0 + r) * HW_DIM + k];
            }
            As[r][kk] = av;
            Bs[r][kk] = bv;
        }
        __syncthreads();

        #pragma unroll
        for (int kk = 0; kk < 32; ++kk) {
            float a[4], bb[4];
            #pragma unroll
            for (int u = 0; u < 4; ++u) a[u] = As[ty * 4 + u][kk];
            #pragma unroll
            for (int v = 0; v < 4; ++v) bb[v] = Bs[tx * 4 + v][kk];
            #pragma unroll
            for (int u = 0; u < 4; ++u)
                #pragma unroll
                for (int v = 0; v < 4; ++v)
                    acc[u][v] += a[u] * bb[v];
        }
        __syncthreads();
    }

    // Scatter epilogue: bin = (h1[c1] + h2[c2]) mod D, signed accumulate.
    float* outb = out + (size_t)b * D_DIM;
    #pragma unroll
    for (int u = 0; u < 4; ++u) {
        const int c1 = i0 + ty * 4 + u;
        const int hh1 = h1[c1];
        const float ss1 = s1[c1];
        #pragma unroll
        for (int v = 0; v < 4; ++v) {
            const int c2 = j0 + tx * 4 + v;
            int bin = hh1 + h2[c2];
            if (bin >= D_DIM) bin -= D_DIM;   // both < D, so one subtract suffices
            atomicAdd(outb + bin, ss1 * s2[c2] * acc[u][v]);
        }
    }
}

extern "C" void kernel_launch(void* const* d_in, const int* in_sizes, int n_in,
                              void* d_out, int out_size, void* d_ws, size_t ws_size,
                              hipStream_t stream) {
    const float* x  = (const float*)d_in[0];  // [16, 512, 14, 14] fp32
    const float* S1 = (const float*)d_in[1];  // [512, 8000] fp32
    const float* S2 = (const float*)d_in[2];  // [512, 8000] fp32
    float* out = (float*)d_out;               // [16, 8000] fp32

    // Workspace layout: h1[512] int | h2[512] int | s1[512] f32 | s2[512] f32
    int*   h1 = (int*)d_ws;
    int*   h2 = h1 + C_DIM;
    float* s1 = (float*)(h2 + C_DIM);
    float* s2 = s1 + C_DIM;

    // Output is re-poisoned before every timed launch — zero it ourselves.
    hipMemsetAsync(d_out, 0, (size_t)out_size * sizeof(float), stream);

    extract_sketch<<<C_DIM, 256, 0, stream>>>(S1, h1, s1);
    extract_sketch<<<C_DIM, 256, 0, stream>>>(S2, h2, s2);

    dim3 grid(C_DIM / 64, C_DIM / 64, B_DIM);
    gram_scatter<<<grid, 256, 0, stream>>>(x, h1, s1, h2, s2, out);
}

// Round 2
// 133.338 us; speedup vs baseline: 2.4026x; 2.4026x over previous
//
#include <hip/hip_runtime.h>

// Problem constants: B=16, C=512, H=W=14 (HW=196), D=8000.
#define B_DIM 16
#define C_DIM 512
#define HW_DIM 196
#define D_DIM 8000

#define KT 28          // 196 = 7*28 -> no K guards
#define BT 128         // block tile: 128x128, 16x16 threads, 8x8 per thread
#define PAD 4          // LDS row pad (stride 132 floats, keeps 16B alignment)

// ---------------------------------------------------------------------------
// Kernel 1: extract (hash, sign) from both dense sketch matrices.
// blockIdx.x in [0,1024): rows 0..511 -> S1, 512..1023 -> S2.
// ---------------------------------------------------------------------------
__global__ __launch_bounds__(256) void extract_both(
    const float* __restrict__ S1, const float* __restrict__ S2,
    int* __restrict__ h, float* __restrict__ s) {
    const int row   = blockIdx.x & (C_DIM - 1);
    const int which = blockIdx.x >> 9;
    const float* S  = which ? S2 : S1;
    const float4* rowp = (const float4*)(S + (size_t)row * D_DIM);
    int*   hp = h + which * C_DIM;
    float* sp = s + which * C_DIM;
    for (int j4 = threadIdx.x; j4 < D_DIM / 4; j4 += 256) {
        float4 v = rowp[j4];
        if (v.x != 0.0f) { hp[row] = 4 * j4 + 0; sp[row] = v.x; }
        if (v.y != 0.0f) { hp[row] = 4 * j4 + 1; sp[row] = v.y; }
        if (v.z != 0.0f) { hp[row] = 4 * j4 + 2; sp[row] = v.z; }
        if (v.w != 0.0f) { hp[row] = 4 * j4 + 3; sp[row] = v.w; }
    }
}

// ---------------------------------------------------------------------------
// Kernel 2: 128x128 Gram tile (G = A*A^T over K=196) + LDS-histogram scatter.
// Each block owns a private 8000-bin LDS histogram; scatter uses LDS float
// atomics only; the histogram is flushed to workspace with plain coalesced
// stores (zero global atomics).
// Grid: (4 j-tiles, 4 i-tiles, 16 batches) = 256 blocks.
// LDS: hist 32000 B + 2 * 28*132*4 B = 61568 B (< 64 KB static limit).
// ---------------------------------------------------------------------------
__global__ __launch_bounds__(256) void gram_hist(
    const float* __restrict__ x,     // [B, C, HW]
    const int* __restrict__ h1, const float* __restrict__ s1,
    const int* __restrict__ h2, const float* __restrict__ s2,
    float* __restrict__ part) {      // [256, D] partial histograms
    const int b  = blockIdx.z;
    const int i0 = blockIdx.y * BT;
    const int j0 = blockIdx.x * BT;
    const float* A = x + (size_t)b * C_DIM * HW_DIM;

    __shared__ float hist[D_DIM];
    __shared__ float At[KT][BT + PAD];   // K-major: fragment reads are float4
    __shared__ float Bt[KT][BT + PAD];

    const int tid = threadIdx.x;
    const int tx  = tid & 15;
    const int ty  = tid >> 4;

    // Zero the histogram (covered by the first k-loop barrier).
    for (int d = tid; d < D_DIM; d += 256) hist[d] = 0.0f;

    float acc[8][8] = {};

    for (int k0 = 0; k0 < HW_DIM; k0 += KT) {
        // Stage two 128x28 tiles, transposed to K-major. 3584 elems each,
        // 14 per thread per tile; global reads coalesced along k.
        #pragma unroll
        for (int l = 0; l < 14; ++l) {
            int idx = l * 256 + tid;        // 0..3583
            int r   = idx / KT;             // 0..127
            int kk  = idx - r * KT;         // 0..27
            int k   = k0 + kk;              // always < 196
            At[kk][r] = A[(size_t)(i0 + r) * HW_DIM + k];
            Bt[kk][r] = A[(size_t)(j0 + r) * HW_DIM + k];
        }
        __syncthreads();

        #pragma unroll
        for (int kk = 0; kk < KT; ++kk) {
            float4 a0 = *(const float4*)&At[kk][ty * 8];
            float4 a1 = *(const float4*)&At[kk][ty * 8 + 4];
            float4 b0 = *(const float4*)&Bt[kk][tx * 8];
            float4 b1 = *(const float4*)&Bt[kk][tx * 8 + 4];
            float a[8] = {a0.x, a0.y, a0.z, a0.w, a1.x, a1.y, a1.z, a1.w};
            float bb[8] = {b0.x, b0.y, b0.z, b0.w, b1.x, b1.y, b1.z, b1.w};
            #pragma unroll
            for (int u = 0; u < 8; ++u)
                #pragma unroll
                for (int v = 0; v < 8; ++v)
                    acc[u][v] += a[u] * bb[v];
        }
        __syncthreads();
    }

    // Scatter into the block-private LDS histogram.
    int hr[8]; float sr[8]; int hc[8]; float sc[8];
    #pragma unroll
    for (int u = 0; u < 8; ++u) {
        hr[u] = h1[i0 + ty * 8 + u];
        sr[u] = s1[i0 + ty * 8 + u];
    }
    #pragma unroll
    for (int v = 0; v < 8; ++v) {
        hc[v] = h2[j0 + tx * 8 + v];
        sc[v] = s2[j0 + tx * 8 + v];
    }
    #pragma unroll
    for (int u = 0; u < 8; ++u)
        #pragma unroll
        for (int v = 0; v < 8; ++v) {
            int bin = hr[u] + hc[v];
            if (bin >= D_DIM) bin -= D_DIM;
            atomicAdd(&hist[bin], sr[u] * sc[v] * acc[u][v]);
        }
    __syncthreads();

    // Flush: plain coalesced stores to the block's private partial slice.
    float* pb = part + (size_t)((b * 4 + blockIdx.y) * 4 + blockIdx.x) * D_DIM;
    for (int d = tid; d < D_DIM; d += 256) pb[d] = hist[d];
}

// ---------------------------------------------------------------------------
// Kernel 3: reduce 16 partials per batch -> out[b, d]. Plain stores (output
// is fully overwritten, so no memset of d_out is needed).
// ---------------------------------------------------------------------------
__global__ __launch_bounds__(256) void reduce_part(
    const float* __restrict__ part, float* __restrict__ out) {
    int idx = blockIdx.x * 256 + threadIdx.x;   // over B*D = 128000
    if (idx >= B_DIM * D_DIM) return;
    int b = idx / D_DIM;
    int d = idx - b * D_DIM;
    const float* p = part + (size_t)b * 16 * D_DIM + d;
    float v = 0.0f;
    #pragma unroll
    for (int t = 0; t < 16; ++t) v += p[(size_t)t * D_DIM];
    out[idx] = v;
}

extern "C" void kernel_launch(void* const* d_in, const int* in_sizes, int n_in,
                              void* d_out, int out_size, void* d_ws, size_t ws_size,
                              hipStream_t stream) {
    const float* x  = (const float*)d_in[0];  // [16, 512, 14, 14] fp32
    const float* S1 = (const float*)d_in[1];  // [512, 8000] fp32
    const float* S2 = (const float*)d_in[2];  // [512, 8000] fp32
    float* out = (float*)d_out;               // [16, 8000] fp32

    // Workspace: h[1024] int | s[1024] f32 | part[256*8000] f32  (~8.2 MB)
    int*   h    = (int*)d_ws;
    float* s    = (float*)(h + 2 * C_DIM);
    float* part = s + 2 * C_DIM;

    extract_both<<<2 * C_DIM, 256, 0, stream>>>(S1, S2, h, s);

    dim3 grid(C_DIM / BT, C_DIM / BT, B_DIM);   // (4, 4, 16)
    gram_hist<<<grid, 256, 0, stream>>>(x, h, s, h + C_DIM, s + C_DIM, part);

    reduce_part<<<(B_DIM * D_DIM + 255) / 256, 256, 0, stream>>>(part, out);
}